// Round 8
// baseline (152.074 us; speedup 1.0000x reference)
//
#include <hip/hip_runtime.h>
#include <hip/hip_fp16.h>

#define NN 1024
#define HH 128
#define QR 2
#define TPB 1024
#define RPB 4

typedef _Float16 f16x2_t __attribute__((ext_vector_type(2)));

__device__ __forceinline__ float dot2(__half2 a, __half2 b, float c) {
#if __has_builtin(__builtin_amdgcn_fdot2)
  return __builtin_amdgcn_fdot2(__builtin_bit_cast(f16x2_t, a),
                                __builtin_bit_cast(f16x2_t, b), c, false);
#else
  return fmaf(__low2float(a), __low2float(b),
              fmaf(__high2float(a), __high2float(b), c));
#endif
}

// packed-f16 relu: max(a, 0) per half (v_pk_max_f16); ROCm lacks __hmax2
__device__ __forceinline__ __half2 relu2(__half2 a) {
#if __has_builtin(__builtin_elementwise_max)
  f16x2_t v = __builtin_bit_cast(f16x2_t, a);
  f16x2_t z = {(_Float16)0.f, (_Float16)0.f};
  return __builtin_bit_cast(__half2, __builtin_elementwise_max(v, z));
#else
  unsigned int av = __builtin_bit_cast(unsigned int, a);
  unsigned int rv;
  asm("v_pk_max_f16 %0, %1, 0" : "=v"(rv) : "v"(av));
  return __builtin_bit_cast(__half2, rv);
#endif
}

__device__ __forceinline__ float4 wmax4(float4 v) {
#pragma unroll
  for (int off = 1; off < 64; off <<= 1) {
    v.x = fmaxf(v.x, __shfl_xor(v.x, off));
    v.y = fmaxf(v.y, __shfl_xor(v.y, off));
    v.z = fmaxf(v.z, __shfl_xor(v.z, off));
    v.w = fmaxf(v.w, __shfl_xor(v.w, off));
  }
  return v;
}
__device__ __forceinline__ float4 wsum4(float4 v) {
#pragma unroll
  for (int off = 1; off < 64; off <<= 1) {
    v.x += __shfl_xor(v.x, off);
    v.y += __shfl_xor(v.y, off);
    v.z += __shfl_xor(v.z, off);
    v.w += __shfl_xor(v.w, off);
  }
  return v;
}

// ---------------- prep: W transposes + edge params (f32 + packed f16) + c0 ----------------
__global__ __launch_bounds__(128)
void prep_kernel(const float* __restrict__ Wq, const float* __restrict__ Wk,
                 const float* __restrict__ Wv, const float* __restrict__ We1,
                 const float* __restrict__ be1, const float* __restrict__ We2,
                 const float* __restrict__ be2, const float* __restrict__ Wc,
                 const float* __restrict__ bc,
                 float* __restrict__ WqT, float* __restrict__ WkT,
                 float* __restrict__ WvT, float* __restrict__ epack,
                 float* __restrict__ c0,
                 __half2* __restrict__ aB, __half2* __restrict__ bB,
                 __half2* __restrict__ uB) {
  __shared__ float su[HH];
  const int d = blockIdx.x;
  const int o = threadIdx.x;
  WqT[d * HH + o] = Wq[o * HH + d];
  WkT[d * HH + o] = Wk[o * HH + d];
  WvT[d * HH + o] = Wv[o * HH + d];
  if (d == 0) {
    // u[t] = sum_e Wc[e] * We2[e][t]   (fold Wc @ We2)
    float uu = 0.f;
    for (int e = 0; e < HH; ++e) uu = fmaf(Wc[e], We2[e * HH + o], uu);
    su[o] = uu;
    epack[o * 4 + 0] = We1[2 * o];
    epack[o * 4 + 1] = We1[2 * o + 1];
    epack[o * 4 + 2] = be1[o];
    epack[o * 4 + 3] = uu;
    if (o == 0) {
      float s = bc[0];
      for (int e = 0; e < HH; ++e) s = fmaf(Wc[e], be2[e], s);
      c0[0] = s;
    }
    __syncthreads();
    if (o < 64) {  // packed f16 over t-pairs (t = 2o, 2o+1)
      aB[o] = __halves2half2(__float2half(We1[4 * o]), __float2half(We1[4 * o + 2]));
      bB[o] = __halves2half2(__float2half(We1[4 * o + 1]), __float2half(We1[4 * o + 3]));
      uB[o] = __halves2half2(__float2half(su[2 * o]), __float2half(su[2 * o + 1]));
    }
  }
}

// ---------------- qkv: f16 outputs, all row-major; q pre-scaled ----------------
__global__ __launch_bounds__(128)
void qkv_kernel(const float* __restrict__ hin,
                const float* __restrict__ WqT, const float* __restrict__ WkT,
                const float* __restrict__ WvT,
                const float* __restrict__ bq, const float* __restrict__ bk,
                const float* __restrict__ bv,
                __half* __restrict__ q16, __half* __restrict__ k16,
                __half* __restrict__ v16) {
  __shared__ __align__(16) float hT[HH][QR];
  const int tid = threadIdx.x;   // output feature o
  const int i0 = blockIdx.x * QR;
#pragma unroll
  for (int r = 0; r < QR; ++r) hT[tid][r] = hin[(i0 + r) * HH + tid];
  __syncthreads();
  float qa0 = 0.f, qa1 = 0.f, ka0 = 0.f, ka1 = 0.f, va0 = 0.f, va1 = 0.f;
#pragma unroll 4
  for (int d = 0; d < HH; ++d) {
    float wq = WqT[d * HH + tid];
    float wk = WkT[d * HH + tid];
    float wv = WvT[d * HH + tid];
    float2 hh = *(const float2*)&hT[d][0];
    qa0 = fmaf(hh.x, wq, qa0); qa1 = fmaf(hh.y, wq, qa1);
    ka0 = fmaf(hh.x, wk, ka0); ka1 = fmaf(hh.y, wk, ka1);
    va0 = fmaf(hh.x, wv, va0); va1 = fmaf(hh.y, wv, va1);
  }
  const float scale = 0.08838834764831845f;  // 1/sqrt(128), folded into q
  float bqv = bq[tid], bkv = bk[tid], bvv = bv[tid];
  q16[(i0 + 0) * HH + tid] = __float2half((qa0 + bqv) * scale);
  q16[(i0 + 1) * HH + tid] = __float2half((qa1 + bqv) * scale);
  k16[(i0 + 0) * HH + tid] = __float2half(ka0 + bkv);
  k16[(i0 + 1) * HH + tid] = __float2half(ka1 + bkv);
  v16[(i0 + 0) * HH + tid] = __float2half(va0 + bvv);
  v16[(i0 + 1) * HH + tid] = __float2half(va1 + bvv);
}

// ---------------- fused attention + edge-weighted coordinate update ----------------
// grid 256, 1024 threads, 4 rows/block, 1 column j per thread.
__global__ __launch_bounds__(TPB, 4)
void fused_kernel(const __half* __restrict__ q16, const __half* __restrict__ k16,
                  const __half* __restrict__ v16, const float* __restrict__ hin,
                  const float* __restrict__ x, const float* __restrict__ epack,
                  const __half2* __restrict__ aB, const __half2* __restrict__ bB,
                  const __half2* __restrict__ uB, const float* __restrict__ c0p,
                  float* __restrict__ out_h, float* __restrict__ out_x) {
  __shared__ __align__(16) float4 sp[NN];          // 16KB unnormalized p, 4 rows per j
  __shared__ __align__(16) float4 sredh[16][HH];   // 32KB PV partials (rows in float4)
  __shared__ __half2 stab[RPB][64];                // 1KB s_i[r][t-pair]
  __shared__ float4 sredm[16], sreds[16], sredx[16], sredy[16];

  const int tid = threadIdx.x;
  const int lane = tid & 63;
  const int wid = tid >> 6;       // 0..15
  const int i0 = blockIdx.x * RPB;
  const int j = tid;

  // ---- phase 0: stab[r][tp] = {We1[2tp]·x_r + be1, We1[2tp+1]·x_r + be1}
  if (tid < 4 * 64) {
    const int r = tid & 3, tp = tid >> 2;
    const float4 ea = ((const float4*)epack)[2 * tp];
    const float4 eb = ((const float4*)epack)[2 * tp + 1];
    float xrx = x[(i0 + r) * 2 + 0], xry = x[(i0 + r) * 2 + 1];
    stab[r][tp] = __halves2half2(
        __float2half(fmaf(ea.x, xrx, fmaf(ea.y, xry, ea.z))),
        __float2half(fmaf(eb.x, xrx, fmaf(eb.y, xry, eb.z))));
  }

  // ---- scores: lane bursts its own 256B k-row (16 x dwordx4, imm offsets); q via s_load
  const float4* kr4 = (const float4*)(k16 + (size_t)j * HH);
  const __half2* q0p = (const __half2*)(q16 + (size_t)(i0 + 0) * HH);
  const __half2* q1p = (const __half2*)(q16 + (size_t)(i0 + 1) * HH);
  const __half2* q2p = (const __half2*)(q16 + (size_t)(i0 + 2) * HH);
  const __half2* q3p = (const __half2*)(q16 + (size_t)(i0 + 3) * HH);
  float s0 = 0.f, s1 = 0.f, s2 = 0.f, s3 = 0.f;
#pragma unroll
  for (int c = 0; c < 16; ++c) {
    float4 raw = kr4[c];
    __half2 k0 = __builtin_bit_cast(__half2, raw.x);
    __half2 k1 = __builtin_bit_cast(__half2, raw.y);
    __half2 k2 = __builtin_bit_cast(__half2, raw.z);
    __half2 k3 = __builtin_bit_cast(__half2, raw.w);
    const int dp = 4 * c;
    s0 = dot2(k0, q0p[dp], s0); s0 = dot2(k1, q0p[dp + 1], s0);
    s0 = dot2(k2, q0p[dp + 2], s0); s0 = dot2(k3, q0p[dp + 3], s0);
    s1 = dot2(k0, q1p[dp], s1); s1 = dot2(k1, q1p[dp + 1], s1);
    s1 = dot2(k2, q1p[dp + 2], s1); s1 = dot2(k3, q1p[dp + 3], s1);
    s2 = dot2(k0, q2p[dp], s2); s2 = dot2(k1, q2p[dp + 1], s2);
    s2 = dot2(k2, q2p[dp + 2], s2); s2 = dot2(k3, q2p[dp + 3], s2);
    s3 = dot2(k0, q3p[dp], s3); s3 = dot2(k1, q3p[dp + 1], s3);
    s3 = dot2(k2, q3p[dp + 2], s3); s3 = dot2(k3, q3p[dp + 3], s3);
  }

  // ---- row max
  float4 mv = wmax4(make_float4(s0, s1, s2, s3));
  if (lane == 0) sredm[wid] = mv;
  __syncthreads();   // also publishes stab
  float4 mm = sredm[0];
#pragma unroll
  for (int w2 = 1; w2 < 16; ++w2) {
    float4 t4 = sredm[w2];
    mm.x = fmaxf(mm.x, t4.x); mm.y = fmaxf(mm.y, t4.y);
    mm.z = fmaxf(mm.z, t4.z); mm.w = fmaxf(mm.w, t4.w);
  }

  // ---- exp -> LDS, row sums
  float e0 = __expf(s0 - mm.x), e1 = __expf(s1 - mm.y);
  float e2 = __expf(s2 - mm.z), e3 = __expf(s3 - mm.w);
  sp[j] = make_float4(e0, e1, e2, e3);
  float4 sv = wsum4(make_float4(e0, e1, e2, e3));
  if (lane == 0) sreds[wid] = sv;
  __syncthreads();   // publishes sp + sreds
  float4 ssv = sreds[0];
#pragma unroll
  for (int w2 = 1; w2 < 16; ++w2) {
    float4 t4 = sreds[w2];
    ssv.x += t4.x; ssv.y += t4.y; ssv.z += t4.z; ssv.w += t4.w;
  }
  const float4 inv4 = make_float4(1.f / ssv.x, 1.f / ssv.y, 1.f / ssv.z, 1.f / ssv.w);

  // ---- agg_h = p @ v: thread = (o-pair, j-chunk), 16 chunks x 64 j
  {
    const int op = tid & 63;        // feature pair (lane) -> coalesced v reads
    const int cc = tid >> 6;        // chunk (wave-uniform)
    float hA0 = 0.f, hA1 = 0.f, hA2 = 0.f, hA3 = 0.f;
    float hB0 = 0.f, hB1 = 0.f, hB2 = 0.f, hB3 = 0.f;
#pragma unroll 4
    for (int jj = 0; jj < NN / 16; ++jj) {
      int jv = cc * (NN / 16) + jj;
      __half2 vv = *(const __half2*)&v16[jv * HH + 2 * op];  // coalesced dword
      float vx = __low2float(vv), vy = __high2float(vv);
      float4 pp = sp[jv];   // uniform LDS b128 broadcast
      hA0 = fmaf(pp.x, vx, hA0); hB0 = fmaf(pp.x, vy, hB0);
      hA1 = fmaf(pp.y, vx, hA1); hB1 = fmaf(pp.y, vy, hB1);
      hA2 = fmaf(pp.z, vx, hA2); hB2 = fmaf(pp.z, vy, hB2);
      hA3 = fmaf(pp.w, vx, hA3); hB3 = fmaf(pp.w, vy, hB3);
    }
    sredh[cc][2 * op + 0] = make_float4(hA0, hA1, hA2, hA3);  // feature 2op, rows 0..3
    sredh[cc][2 * op + 1] = make_float4(hB0, hB1, hB2, hB3);  // feature 2op+1
  }

  // ---- edge loop, packed f16 over t-pairs, f32 accumulate via dot2 (4 rows share w_j)
  float2 xj = *(const float2*)&x[2 * j];
  __half2 xjx2 = __float2half2_rn(xj.x);
  __half2 xjy2 = __float2half2_rn(xj.y);
  float wa0 = 0.f, wa1 = 0.f, wa2 = 0.f, wa3 = 0.f;
#pragma unroll 8
  for (int tp = 0; tp < 64; ++tp) {
    __half2 a2 = aB[tp], b2 = bB[tp], u2 = uB[tp];   // uniform -> s_load
    __half2 w2h = __hfma2(a2, xjx2, __hmul2(b2, xjy2));
    wa0 = dot2(u2, relu2(__hsub2(stab[0][tp], w2h)), wa0);
    wa1 = dot2(u2, relu2(__hsub2(stab[1][tp], w2h)), wa1);
    wa2 = dot2(u2, relu2(__hsub2(stab[2][tp], w2h)), wa2);
    wa3 = dot2(u2, relu2(__hsub2(stab[3][tp], w2h)), wa3);
  }
  const float c0v = c0p[0];
  float cw0 = e0 * (wa0 + c0v), cw1 = e1 * (wa1 + c0v);
  float cw2 = e2 * (wa2 + c0v), cw3 = e3 * (wa3 + c0v);
  float xi0x = x[(i0 + 0) * 2 + 0], xi0y = x[(i0 + 0) * 2 + 1];
  float xi1x = x[(i0 + 1) * 2 + 0], xi1y = x[(i0 + 1) * 2 + 1];
  float xi2x = x[(i0 + 2) * 2 + 0], xi2y = x[(i0 + 2) * 2 + 1];
  float xi3x = x[(i0 + 3) * 2 + 0], xi3y = x[(i0 + 3) * 2 + 1];
  float4 rx = wsum4(make_float4(cw0 * (xi0x - xj.x), cw1 * (xi1x - xj.x),
                                cw2 * (xi2x - xj.x), cw3 * (xi3x - xj.x)));
  float4 ry = wsum4(make_float4(cw0 * (xi0y - xj.y), cw1 * (xi1y - xj.y),
                                cw2 * (xi2y - xj.y), cw3 * (xi3y - xj.y)));
  if (lane == 0) { sredx[wid] = rx; sredy[wid] = ry; }

  __syncthreads();   // publishes sredh + sredx/y

  // ---- epilogue: feature-per-thread, float4 over rows (b128 reads, conflict-free)
  if (tid < HH) {
    float4 acc = sredh[0][tid];
#pragma unroll
    for (int c2 = 1; c2 < 16; ++c2) {
      float4 t4 = sredh[c2][tid];
      acc.x += t4.x; acc.y += t4.y; acc.z += t4.z; acc.w += t4.w;
    }
    out_h[(i0 + 0) * HH + tid] = hin[(i0 + 0) * HH + tid] + acc.x * inv4.x;
    out_h[(i0 + 1) * HH + tid] = hin[(i0 + 1) * HH + tid] + acc.y * inv4.y;
    out_h[(i0 + 2) * HH + tid] = hin[(i0 + 2) * HH + tid] + acc.z * inv4.z;
    out_h[(i0 + 3) * HH + tid] = hin[(i0 + 3) * HH + tid] + acc.w * inv4.w;
  }
  if (tid < 4) {
    const int r = tid;
    float sx = 0.f, sy = 0.f;
#pragma unroll
    for (int w2 = 0; w2 < 16; ++w2) {
      sx += ((const float*)&sredx[w2])[r];
      sy += ((const float*)&sredy[w2])[r];
    }
    float invr = ((const float*)&inv4)[r];
    out_x[(i0 + r) * 2 + 0] = x[(i0 + r) * 2 + 0] + sx * invr;
    out_x[(i0 + r) * 2 + 1] = x[(i0 + r) * 2 + 1] + sy * invr;
  }
}

extern "C" void kernel_launch(void* const* d_in, const int* in_sizes, int n_in,
                              void* d_out, int out_size, void* d_ws, size_t ws_size,
                              hipStream_t stream) {
  (void)in_sizes; (void)n_in; (void)out_size; (void)ws_size;
  const float* h   = (const float*)d_in[0];
  const float* x   = (const float*)d_in[1];
  // d_in[2] = batch (all zeros, unused)
  const float* Wq  = (const float*)d_in[3];
  const float* bq  = (const float*)d_in[4];
  const float* Wk  = (const float*)d_in[5];
  const float* bk  = (const float*)d_in[6];
  const float* Wv  = (const float*)d_in[7];
  const float* bv  = (const float*)d_in[8];
  const float* We1 = (const float*)d_in[9];
  const float* be1 = (const float*)d_in[10];
  const float* We2 = (const float*)d_in[11];
  const float* be2 = (const float*)d_in[12];
  const float* Wc  = (const float*)d_in[13];
  const float* bc  = (const float*)d_in[14];

  float* ws   = (float*)d_ws;
  float* WqT  = ws;                   // 16384
  float* WkT  = WqT + HH * HH;        // 16384
  float* WvT  = WkT + HH * HH;        // 16384
  float* ep   = WvT + HH * HH;        // 512 (f32 {a,b,be1,u} per t)
  float* c0   = ep + 4 * HH;          // 8 (padded)
  __half* q16 = (__half*)(c0 + 8);    // N*H halves (scaled q), row-major
  __half* k16 = q16 + NN * HH;        // N*H halves, row-major [j][d]
  __half* v16 = k16 + NN * HH;        // N*H halves, row-major
  __half2* aB = (__half2*)(v16 + NN * HH);  // 64
  __half2* bB = aB + 64;                    // 64
  __half2* uB = bB + 64;                    // 64

  float* out_h = (float*)d_out;            // N*H
  float* out_x = out_h + NN * HH;          // N*2

  prep_kernel<<<dim3(HH), dim3(128), 0, stream>>>(
      Wq, Wk, Wv, We1, be1, We2, be2, Wc, bc, WqT, WkT, WvT, ep, c0, aB, bB, uB);
  qkv_kernel<<<dim3(NN / QR), dim3(128), 0, stream>>>(
      h, WqT, WkT, WvT, bq, bk, bv, q16, k16, v16);
  fused_kernel<<<dim3(NN / RPB), dim3(TPB), 0, stream>>>(
      q16, k16, v16, h, x, ep, aB, bB, uB, c0, out_h, out_x);
}

// Round 9
// 124.360 us; speedup vs baseline: 1.2229x; 1.2229x over previous
//
#include <hip/hip_runtime.h>
#include <hip/hip_fp16.h>

#define NN 1024
#define HH 128
#define QR 2
#define TPB 512
#define RPB 2

typedef _Float16 f16x2_t __attribute__((ext_vector_type(2)));

__device__ __forceinline__ float dot2(__half2 a, __half2 b, float c) {
#if __has_builtin(__builtin_amdgcn_fdot2)
  return __builtin_amdgcn_fdot2(__builtin_bit_cast(f16x2_t, a),
                                __builtin_bit_cast(f16x2_t, b), c, false);
#else
  return fmaf(__low2float(a), __low2float(b),
              fmaf(__high2float(a), __high2float(b), c));
#endif
}

// packed-f16 relu: max(a, 0) per half (v_pk_max_f16); ROCm lacks __hmax2
__device__ __forceinline__ __half2 relu2(__half2 a) {
#if __has_builtin(__builtin_elementwise_max)
  f16x2_t v = __builtin_bit_cast(f16x2_t, a);
  f16x2_t z = {(_Float16)0.f, (_Float16)0.f};
  return __builtin_bit_cast(__half2, __builtin_elementwise_max(v, z));
#else
  unsigned int av = __builtin_bit_cast(unsigned int, a);
  unsigned int rv;
  asm("v_pk_max_f16 %0, %1, 0" : "=v"(rv) : "v"(av));
  return __builtin_bit_cast(__half2, rv);
#endif
}

__device__ __forceinline__ float2 wmax2(float2 v) {
#pragma unroll
  for (int off = 1; off < 64; off <<= 1) {
    v.x = fmaxf(v.x, __shfl_xor(v.x, off));
    v.y = fmaxf(v.y, __shfl_xor(v.y, off));
  }
  return v;
}
__device__ __forceinline__ float2 wsum2(float2 v) {
#pragma unroll
  for (int off = 1; off < 64; off <<= 1) {
    v.x += __shfl_xor(v.x, off);
    v.y += __shfl_xor(v.y, off);
  }
  return v;
}

// ---------------- prep: W transposes + edge params (f32 + packed f16) + c0 ----------------
__global__ __launch_bounds__(128)
void prep_kernel(const float* __restrict__ Wq, const float* __restrict__ Wk,
                 const float* __restrict__ Wv, const float* __restrict__ We1,
                 const float* __restrict__ be1, const float* __restrict__ We2,
                 const float* __restrict__ be2, const float* __restrict__ Wc,
                 const float* __restrict__ bc,
                 float* __restrict__ WqT, float* __restrict__ WkT,
                 float* __restrict__ WvT, float* __restrict__ epack,
                 float* __restrict__ c0,
                 __half2* __restrict__ aB, __half2* __restrict__ bB,
                 __half2* __restrict__ uB) {
  __shared__ float su[HH];
  const int d = blockIdx.x;
  const int o = threadIdx.x;
  WqT[d * HH + o] = Wq[o * HH + d];
  WkT[d * HH + o] = Wk[o * HH + d];
  WvT[d * HH + o] = Wv[o * HH + d];
  if (d == 0) {
    // u[t] = sum_e Wc[e] * We2[e][t]   (fold Wc @ We2)
    float uu = 0.f;
    for (int e = 0; e < HH; ++e) uu = fmaf(Wc[e], We2[e * HH + o], uu);
    su[o] = uu;
    epack[o * 4 + 0] = We1[2 * o];
    epack[o * 4 + 1] = We1[2 * o + 1];
    epack[o * 4 + 2] = be1[o];
    epack[o * 4 + 3] = uu;
    if (o == 0) {
      float s = bc[0];
      for (int e = 0; e < HH; ++e) s = fmaf(Wc[e], be2[e], s);
      c0[0] = s;
    }
    __syncthreads();
    if (o < 64) {  // packed f16 over t-pairs (t = 2o, 2o+1)
      aB[o] = __halves2half2(__float2half(We1[4 * o]), __float2half(We1[4 * o + 2]));
      bB[o] = __halves2half2(__float2half(We1[4 * o + 1]), __float2half(We1[4 * o + 3]));
      uB[o] = __halves2half2(__float2half(su[2 * o]), __float2half(su[2 * o + 1]));
    }
  }
}

// ---------------- qkv: q f16 (scaled), k in k8[c][j][8] f16 groups, v f32 ----------------
__global__ __launch_bounds__(128)
void qkv_kernel(const float* __restrict__ hin,
                const float* __restrict__ WqT, const float* __restrict__ WkT,
                const float* __restrict__ WvT,
                const float* __restrict__ bq, const float* __restrict__ bk,
                const float* __restrict__ bv,
                __half* __restrict__ q16, __half* __restrict__ k8,
                float* __restrict__ vF) {
  __shared__ __align__(16) float hT[HH][QR];
  const int tid = threadIdx.x;   // output feature o
  const int i0 = blockIdx.x * QR;
#pragma unroll
  for (int r = 0; r < QR; ++r) hT[tid][r] = hin[(i0 + r) * HH + tid];
  __syncthreads();
  float qa0 = 0.f, qa1 = 0.f, ka0 = 0.f, ka1 = 0.f, va0 = 0.f, va1 = 0.f;
#pragma unroll 4
  for (int d = 0; d < HH; ++d) {
    float wq = WqT[d * HH + tid];
    float wk = WkT[d * HH + tid];
    float wv = WvT[d * HH + tid];
    float2 hh = *(const float2*)&hT[d][0];
    qa0 = fmaf(hh.x, wq, qa0); qa1 = fmaf(hh.y, wq, qa1);
    ka0 = fmaf(hh.x, wk, ka0); ka1 = fmaf(hh.y, wk, ka1);
    va0 = fmaf(hh.x, wv, va0); va1 = fmaf(hh.y, wv, va1);
  }
  const float scale = 0.08838834764831845f;  // 1/sqrt(128), folded into q
  float bqv = bq[tid], bkv = bk[tid], bvv = bv[tid];
  q16[(i0 + 0) * HH + tid] = __float2half((qa0 + bqv) * scale);
  q16[(i0 + 1) * HH + tid] = __float2half((qa1 + bqv) * scale);
  // k8: feature group c = o/8, slot o%8 -> 16B per (c, j), coalesced read side
  const int c = tid >> 3, slot = tid & 7;
  k8[(size_t)((c * NN + i0 + 0) << 3) + slot] = __float2half(ka0 + bkv);
  k8[(size_t)((c * NN + i0 + 1) << 3) + slot] = __float2half(ka1 + bkv);
  vF[(i0 + 0) * HH + tid] = va0 + bvv;
  vF[(i0 + 1) * HH + tid] = va1 + bvv;
}

// ---------------- fused attention + edge-weighted coordinate update ----------------
// grid 512, 512 threads, 2 rows/block, cols j0=tid, j1=tid+512. 2 blocks/CU.
__global__ __launch_bounds__(TPB, 4)
void fused_kernel(const __half* __restrict__ q16, const __half* __restrict__ k8,
                  const float* __restrict__ vF, const float* __restrict__ hin,
                  const float* __restrict__ x, const float* __restrict__ epack,
                  const __half2* __restrict__ aB, const __half2* __restrict__ bB,
                  const __half2* __restrict__ uB, const float* __restrict__ c0p,
                  float* __restrict__ out_h, float* __restrict__ out_x) {
  __shared__ __align__(16) float2 sp2[NN];           // 8KB  p{row0,row1} per j
  __shared__ __align__(16) float4 sredh[16][32][2];  // 16KB PV partials
  __shared__ __half2 stab[RPB][64];                  // 512B s_i[r][t-pair]
  __shared__ float2 sredm[8], sreds[8], sredx[8], sredy[8];

  const int tid = threadIdx.x;
  const int lane = tid & 63;
  const int wid = tid >> 6;       // 0..7
  const int i0 = blockIdx.x * RPB;
  const int j0 = tid, j1 = tid + TPB;

  // ---- phase 0: stab[r][tp] = {We1[2tp]·x_r + be1, We1[2tp+1]·x_r + be1}
  if (tid < 2 * 64) {
    const int r = tid & 1, tp = tid >> 1;
    const float4 ea = ((const float4*)epack)[2 * tp];
    const float4 eb = ((const float4*)epack)[2 * tp + 1];
    float xrx = x[(i0 + r) * 2 + 0], xry = x[(i0 + r) * 2 + 1];
    stab[r][tp] = __halves2half2(
        __float2half(fmaf(ea.x, xrx, fmaf(ea.y, xry, ea.z))),
        __float2half(fmaf(eb.x, xrx, fmaf(eb.y, xry, eb.z))));
  }

  // ---- scores: 16 iters, 2 coalesced dwordx4 k-loads, q via s_load
  const __half2* q0p = (const __half2*)(q16 + (size_t)(i0 + 0) * HH);
  const __half2* q1p = (const __half2*)(q16 + (size_t)(i0 + 1) * HH);
  const float4* k84 = (const float4*)k8;
  float s00 = 0.f, s01 = 0.f, s10 = 0.f, s11 = 0.f;   // [row][col]
#pragma unroll
  for (int c = 0; c < 16; ++c) {
    float4 ka = k84[c * NN + j0];   // lanes consecutive -> 1KB coalesced
    float4 kb = k84[c * NN + j1];
    __half2 a0 = __builtin_bit_cast(__half2, ka.x);
    __half2 a1 = __builtin_bit_cast(__half2, ka.y);
    __half2 a2 = __builtin_bit_cast(__half2, ka.z);
    __half2 a3 = __builtin_bit_cast(__half2, ka.w);
    __half2 b0 = __builtin_bit_cast(__half2, kb.x);
    __half2 b1 = __builtin_bit_cast(__half2, kb.y);
    __half2 b2 = __builtin_bit_cast(__half2, kb.z);
    __half2 b3 = __builtin_bit_cast(__half2, kb.w);
    __half2 qa0 = q0p[4 * c + 0], qa1 = q0p[4 * c + 1];
    __half2 qa2 = q0p[4 * c + 2], qa3 = q0p[4 * c + 3];
    __half2 qb0 = q1p[4 * c + 0], qb1 = q1p[4 * c + 1];
    __half2 qb2 = q1p[4 * c + 2], qb3 = q1p[4 * c + 3];
    s00 = dot2(a0, qa0, s00); s00 = dot2(a1, qa1, s00);
    s00 = dot2(a2, qa2, s00); s00 = dot2(a3, qa3, s00);
    s01 = dot2(b0, qa0, s01); s01 = dot2(b1, qa1, s01);
    s01 = dot2(b2, qa2, s01); s01 = dot2(b3, qa3, s01);
    s10 = dot2(a0, qb0, s10); s10 = dot2(a1, qb1, s10);
    s10 = dot2(a2, qb2, s10); s10 = dot2(a3, qb3, s10);
    s11 = dot2(b0, qb0, s11); s11 = dot2(b1, qb1, s11);
    s11 = dot2(b2, qb2, s11); s11 = dot2(b3, qb3, s11);
  }

  // ---- row max
  float2 mv = wmax2(make_float2(fmaxf(s00, s01), fmaxf(s10, s11)));
  if (lane == 0) sredm[wid] = mv;
  __syncthreads();   // publishes stab + sredm
  float2 mm = sredm[0];
#pragma unroll
  for (int w2 = 1; w2 < 8; ++w2) {
    float2 t2 = sredm[w2];
    mm.x = fmaxf(mm.x, t2.x); mm.y = fmaxf(mm.y, t2.y);
  }

  // ---- exp -> LDS (f32 rows), row sums
  float e00 = __expf(s00 - mm.x), e01 = __expf(s01 - mm.x);
  float e10 = __expf(s10 - mm.y), e11 = __expf(s11 - mm.y);
  sp2[j0] = make_float2(e00, e10);
  sp2[j1] = make_float2(e01, e11);
  float2 sv = wsum2(make_float2(e00 + e01, e10 + e11));
  if (lane == 0) sreds[wid] = sv;
  __syncthreads();   // publishes sp2 + sreds
  float2 ssv = sreds[0];
#pragma unroll
  for (int w2 = 1; w2 < 8; ++w2) { ssv.x += sreds[w2].x; ssv.y += sreds[w2].y; }
  const float inv0 = 1.f / ssv.x, inv1 = 1.f / ssv.y;

  // ---- agg_h = p @ v: thread = (4 features, j-chunk), 16 chunks x 64 j, f32 v
  {
    const int op2 = tid & 31;       // features 4*op2..4*op2+3
    const int cc = tid >> 5;        // 0..15
    float4 ar0 = make_float4(0.f, 0.f, 0.f, 0.f);
    float4 ar1 = make_float4(0.f, 0.f, 0.f, 0.f);
#pragma unroll 4
    for (int jj = 0; jj < NN / 16; ++jj) {
      int jv = cc * (NN / 16) + jj;
      float4 vv = ((const float4*)vF)[jv * 32 + op2];  // coalesced dwordx4
      float2 pp = sp2[jv];                             // uniform LDS b64
      ar0.x = fmaf(pp.x, vv.x, ar0.x); ar0.y = fmaf(pp.x, vv.y, ar0.y);
      ar0.z = fmaf(pp.x, vv.z, ar0.z); ar0.w = fmaf(pp.x, vv.w, ar0.w);
      ar1.x = fmaf(pp.y, vv.x, ar1.x); ar1.y = fmaf(pp.y, vv.y, ar1.y);
      ar1.z = fmaf(pp.y, vv.z, ar1.z); ar1.w = fmaf(pp.y, vv.w, ar1.w);
    }
    sredh[cc][op2][0] = ar0;
    sredh[cc][op2][1] = ar1;
  }

  // ---- edge loop, packed f16, 2 cols x 2 rows per thread
  float2 xja = *(const float2*)&x[2 * j0];
  float2 xjb = *(const float2*)&x[2 * j1];
  __half2 xax = __float2half2_rn(xja.x), xay = __float2half2_rn(xja.y);
  __half2 xbx = __float2half2_rn(xjb.x), xby = __float2half2_rn(xjb.y);
  float wa00 = 0.f, wa01 = 0.f, wa10 = 0.f, wa11 = 0.f;   // [row][col]
#pragma unroll 8
  for (int tp = 0; tp < 64; ++tp) {
    __half2 a2 = aB[tp], b2 = bB[tp], u2 = uB[tp];   // uniform -> s_load
    __half2 wA = __hfma2(a2, xax, __hmul2(b2, xay));
    __half2 wB = __hfma2(a2, xbx, __hmul2(b2, xby));
    __half2 s0t = stab[0][tp], s1t = stab[1][tp];
    wa00 = dot2(u2, relu2(__hsub2(s0t, wA)), wa00);
    wa01 = dot2(u2, relu2(__hsub2(s0t, wB)), wa01);
    wa10 = dot2(u2, relu2(__hsub2(s1t, wA)), wa10);
    wa11 = dot2(u2, relu2(__hsub2(s1t, wB)), wa11);
  }
  const float c0v = c0p[0];
  float cw00 = e00 * (wa00 + c0v), cw01 = e01 * (wa01 + c0v);
  float cw10 = e10 * (wa10 + c0v), cw11 = e11 * (wa11 + c0v);
  float xi0x = x[i0 * 2 + 0], xi0y = x[i0 * 2 + 1];
  float xi1x = x[i0 * 2 + 2], xi1y = x[i0 * 2 + 3];
  float2 rx = wsum2(make_float2(
      fmaf(cw00, xi0x - xja.x, cw01 * (xi0x - xjb.x)),
      fmaf(cw10, xi1x - xja.x, cw11 * (xi1x - xjb.x))));
  float2 ry = wsum2(make_float2(
      fmaf(cw00, xi0y - xja.y, cw01 * (xi0y - xjb.y)),
      fmaf(cw10, xi1y - xja.y, cw11 * (xi1y - xjb.y))));
  if (lane == 0) { sredx[wid] = rx; sredy[wid] = ry; }

  __syncthreads();   // publishes sredh + sredx/y

  // ---- epilogue
  if (tid < 2 * HH) {
    const int f = tid & 127, r = tid >> 7;
    const int o2 = f >> 2, fi = f & 3;
    float acc = 0.f;
#pragma unroll
    for (int c2 = 0; c2 < 16; ++c2)
      acc += ((const float*)&sredh[c2][o2][r])[fi];
    float invr = r ? inv1 : inv0;
    out_h[(i0 + r) * HH + f] = hin[(i0 + r) * HH + f] + acc * invr;
  }
  if (tid < 2) {
    const int r = tid;
    float sx = 0.f, sy = 0.f;
#pragma unroll
    for (int w2 = 0; w2 < 8; ++w2) {
      sx += r ? sredx[w2].y : sredx[w2].x;
      sy += r ? sredy[w2].y : sredy[w2].x;
    }
    float invr = r ? inv1 : inv0;
    out_x[(i0 + r) * 2 + 0] = x[(i0 + r) * 2 + 0] + sx * invr;
    out_x[(i0 + r) * 2 + 1] = x[(i0 + r) * 2 + 1] + sy * invr;
  }
}

extern "C" void kernel_launch(void* const* d_in, const int* in_sizes, int n_in,
                              void* d_out, int out_size, void* d_ws, size_t ws_size,
                              hipStream_t stream) {
  (void)in_sizes; (void)n_in; (void)out_size; (void)ws_size;
  const float* h   = (const float*)d_in[0];
  const float* x   = (const float*)d_in[1];
  // d_in[2] = batch (all zeros, unused)
  const float* Wq  = (const float*)d_in[3];
  const float* bq  = (const float*)d_in[4];
  const float* Wk  = (const float*)d_in[5];
  const float* bk  = (const float*)d_in[6];
  const float* Wv  = (const float*)d_in[7];
  const float* bv  = (const float*)d_in[8];
  const float* We1 = (const float*)d_in[9];
  const float* be1 = (const float*)d_in[10];
  const float* We2 = (const float*)d_in[11];
  const float* be2 = (const float*)d_in[12];
  const float* Wc  = (const float*)d_in[13];
  const float* bc  = (const float*)d_in[14];

  float* ws   = (float*)d_ws;
  float* WqT  = ws;                   // 16384 f32
  float* WkT  = WqT + HH * HH;
  float* WvT  = WkT + HH * HH;
  float* ep   = WvT + HH * HH;        // 512 f32
  float* c0   = ep + 4 * HH;          // 8 (padded)
  __half* q16 = (__half*)(c0 + 8);    // N*H halves (scaled q), row-major
  __half* k8  = q16 + NN * HH;        // N*H halves, [c][j][8] groups
  float* vF   = (float*)(k8 + NN * HH);  // N*H f32, row-major
  __half2* aB = (__half2*)(vF + NN * HH);  // 64
  __half2* bB = aB + 64;
  __half2* uB = bB + 64;

  float* out_h = (float*)d_out;            // N*H
  float* out_x = out_h + NN * HH;          // N*2

  prep_kernel<<<dim3(HH), dim3(128), 0, stream>>>(
      Wq, Wk, Wv, We1, be1, We2, be2, Wc, bc, WqT, WkT, WvT, ep, c0, aB, bB, uB);
  qkv_kernel<<<dim3(NN / QR), dim3(128), 0, stream>>>(
      h, WqT, WkT, WvT, bq, bk, bv, q16, k8, vF);
  fused_kernel<<<dim3(NN / RPB), dim3(TPB), 0, stream>>>(
      q16, k8, vF, h, x, ep, aB, bB, uB, c0, out_h, out_x);
}